// Round 7
// baseline (4206.790 us; speedup 1.0000x reference)
//
#include <hip/hip_runtime.h>
#include <stdint.h>

#define D 1024

typedef unsigned long long u64;
typedef unsigned int u32;

// ---------- monotonic float<->uint mapping for atomic max ----------
__device__ __forceinline__ u32 enc_f(float f) {
    u32 b = __float_as_uint(f);
    return (b & 0x80000000u) ? ~b : (b | 0x80000000u);
}
__device__ __forceinline__ float dec_f(u32 u) {
    u32 b = (u & 0x80000000u) ? (u ^ 0x80000000u) : ~u;
    return __uint_as_float(b);
}

// LDS-only barrier: synchronizes DS traffic but does NOT drain vmcnt.
// Global-store visibility is handled by wave specialization: only waves 8-15
// issue global stores; they retire them with an explicit vmcnt(0) at the top
// of the NEXT iteration's P2 (while compute waves run P2), so B2 of iter k+1
// is the visibility fence for iter k's stores. Reads inside the one-iteration
// staleness window (next-P2 row loads) are substituted from LDS history.
__device__ __forceinline__ void barrier_lds_only() {
    __builtin_amdgcn_sched_barrier(0);
    asm volatile("s_waitcnt lgkmcnt(0)" ::: "memory");
    __builtin_amdgcn_s_barrier();
    asm volatile("" ::: "memory");
    __builtin_amdgcn_sched_barrier(0);
}

// ---------- kernel A: max(X), max|X| ----------
__global__ void k_maxred(const float* __restrict__ X, u32* scal) {
    float mx = -INFINITY, ma = 0.f;
    int stride = gridDim.x * blockDim.x;
    for (int i = blockIdx.x * blockDim.x + threadIdx.x; i < D * D; i += stride) {
        float v = X[i];
        mx = fmaxf(mx, v);
        ma = fmaxf(ma, fabsf(v));
    }
    for (int o = 32; o; o >>= 1) {
        mx = fmaxf(mx, __shfl_xor(mx, o));
        ma = fmaxf(ma, __shfl_xor(ma, o));
    }
    if ((threadIdx.x & 63) == 0) {
        atomicMax(&scal[0], enc_f(mx));  // max_sim
        atomicMax(&scal[1], enc_f(ma));  // max|X|
    }
}

// ---------- kernel B: init interleaved (dist, cross) float2 matrix ----------
__global__ void k_init(const float* __restrict__ X, const float* __restrict__ W,
                       float2* __restrict__ dc, const u32* __restrict__ scal) {
    int idx = blockIdx.x * blockDim.x + threadIdx.x;
    if (idx >= D * D) return;
    float max_sim = dec_f(scal[0]);
    float MAXD = __fmul_rn(dec_f(scal[1]), 1000.0f);
    int i = idx >> 10, j = idx & (D - 1);
    float x = X[idx];
    // X is bitwise symmetric (0.5*(A+A^T)), so this matches max_sim - X[min][max]
    float di = (i == j) ? MAXD : __fsub_rn(max_sim, x);
    float cx = (i == j) ? 0.0f : (W[idx] + W[j * D + i]);  // one addend is exactly 0
    dc[idx] = make_float2(di, cx);
}

// ---------- kernel B2: initial per-row (min,argmin) over upper triangle ----------
__global__ void k_rowmin(const float2* __restrict__ dc, float* __restrict__ values_g,
                         int* __restrict__ indices_g, const u32* __restrict__ scal) {
    int r = blockIdx.x;
    int lane = threadIdx.x;  // 64 threads = 1 wave
    float MAXD = __fmul_rn(dec_f(scal[1]), 1000.0f);
    u64 best = ((u64)__float_as_uint(MAXD) << 32);  // (MAXD, idx 0) like jnp.argmin on all-MAXD row
    const float4* row4 = (const float4*)(dc + (size_t)r * D);
    for (int c = lane; c < D / 2; c += 64) {
        float4 q = row4[c];
        int j0 = c << 1;
        if (j0 > r) {
            u64 k = ((u64)__float_as_uint(q.x) << 32) | (u32)j0;
            if (k < best) best = k;
        }
        if (j0 + 1 > r) {
            u64 k = ((u64)__float_as_uint(q.z) << 32) | (u32)(j0 + 1);
            if (k < best) best = k;
        }
    }
    for (int o = 32; o; o >>= 1) {
        u64 k2 = __shfl_xor(best, o);
        if (k2 < best) best = k2;
    }
    if (lane == 0) {
        values_g[r] = __uint_as_float((u32)(best >> 32));
        indices_g[r] = (int)(best & 0xffffffffu);
    }
}

// ---------- kernel C: persistent single-block HAC loop, wave-specialized ----------
// Waves 0-7 (compute): P2 for 2 rows per thread (c0=t, c1=t+512); they issue
//   NO global stores ever, so their load waits never retire store traffic.
// Waves 8-15 (store): in P2 they only s_waitcnt vmcnt(0) (retires LAST iter's
//   stores -> visible to all from B2 on); in P3 they read (nv,ncx) from LDS
//   and issue this iter's row-m1 (coalesced) + col-m1 (scattered) stores.
// Both barriers are LDS-only: the 1024-line scatter drain overlaps a FULL
// iteration of compute instead of stalling B3.
// Row loads are UNCONDITIONAL (issued right after s_best decode, round-4
// structure); staleness (one-iteration window, rows/col pm1 only) is fixed
// AFTER the load via LDS-history substitution:
//   m==pm1   -> whole row from newv_h[pb]/crossv_h[pb]
//   col==pm1 -> single entry newv_h[pb][m] (symmetry: dc[m][pm1]==newv_prev[m])
// Rescans run after B2, where the previous iter's stores are already retired
// -> no substitution needed there (current col m1 still comes from newv LDS).
__global__ void __launch_bounds__(1024) k_hac(
        float2* __restrict__ dc,
        const float* __restrict__ values_g, const int* __restrict__ indices_g,
        int* __restrict__ labels_g, const u32* __restrict__ scal) {
    __shared__ __align__(16) float values_l[D];
    __shared__ float values_stage[D];   // P3 scan results (restored next P2)
    __shared__ int indices_l[D];
    __shared__ __align__(16) float newv_h[2][D];    // cur/prev new dist row
    __shared__ __align__(16) float crossv_h[2][D];  // cur/prev new cross row
    __shared__ float cs_l[D];
    __shared__ unsigned char dead_l[D];
    __shared__ unsigned char marked_l[D];  // row staged in P3 -> restore next P2
    __shared__ int slot_l[D];   // leaf -> active slot id
    __shared__ int label_l[D];
    __shared__ double within_l[D];
    __shared__ double energy_l[D];
    __shared__ int rlist[2][D];
    __shared__ int nrec[2];
    __shared__ u64 s_best[2];   // double-buffered global-argmin accumulator
    __shared__ float s_cross12;
    __shared__ int s_takeP, s_m1P, s_labP;  // deferred cut (applied next iter)

    const int t = threadIdx.x;
    const int lane = t & 63, wid = t >> 6;
    const float MAXD = __fmul_rn(dec_f(scal[1]), 1000.0f);
    const u32 MAXDb = __float_as_uint(MAXD);

    values_l[t] = values_g[t];
    indices_l[t] = indices_g[t];
    cs_l[t] = 1.0f;
    dead_l[t] = 0;
    marked_l[t] = 0;
    slot_l[t] = t;
    label_l[t] = t;
    within_l[t] = 0.0;
    energy_l[t] = 0.0;
    if (t == 0) {
        s_takeP = 0; s_m1P = -1; s_labP = 0;
        nrec[0] = 0; nrec[1] = 0;
        s_best[0] = ~0ull; s_best[1] = ~0ull;
    }
    __syncthreads();
    // boot publish: per-wave reduce over own 64 rows -> atomicMin into s_best[0]
    {
        u64 key = ((u64)__float_as_uint(values_l[t]) << 32) | ((u32)t << 10) |
                  (u32)indices_l[t];
        for (int o = 32; o; o >>= 1) {
            u64 k2 = __shfl_xor(key, o);
            if (k2 < key) key = k2;
        }
        if (lane == 0) atomicMin(&s_best[0], key);
    }
    __syncthreads();

    float pf0 = 0.f, pf1 = 0.f, pf2 = 0.f, pf3 = 0.f;  // prefetch sinks

    for (int it = 0; it < D - 1; ++it) {
        const int cb = it & 1, pb = cb ^ 1;

        // ================= P2 =================
        const u64 bk = s_best[cb];  // one LDS read -> m1 AND m2
        const int m1 = (int)((bk >> 10) & 1023);
        const int m2 = (int)(bk & 1023);
        const int c0 = (wid < 8) ? t : (t - 512);
        const int c1 = c0 + 512;
        float ncs = 0.f;

        if (wid < 8) {
            // global row loads FIRST: unconditional, depend only on s_best
            const float2 v1a = dc[(size_t)m1 * D + c0];
            const float2 v1b = dc[(size_t)m1 * D + c1];
            const float2 v2a = dc[(size_t)m2 * D + c0];
            const float2 v2b = dc[(size_t)m2 * D + c1];

            // hoisted independent LDS reads (issue in parallel)
            const int pm1 = s_m1P;  // prev m1: its stores may still be in flight
            const float cs1 = cs_l[m1], cs2 = cs_l[m2];
            float va = values_l[c0], vb = values_l[c1];
            const float sga = values_stage[c0], sgb = values_stage[c1];
            const int mka = marked_l[c0], mkb = marked_l[c1];
            const int dda = dead_l[c0], ddb = dead_l[c1];
            int ia = indices_l[c0], ib = indices_l[c1];
            const int sla = slot_l[c0], slb = slot_l[c1];
            const int takeP = s_takeP, labP = s_labP;
            if (t == 0) s_best[pb] = ~0ull;  // reset for this iter's publishers

            ncs = __fadd_rn(cs1, cs2);
            const bool h1 = (m1 == pm1), h2 = (m2 == pm1);

            // restore staged P3 results; freeze m2
            if (mka) { va = sga; values_l[c0] = va; marked_l[c0] = 0; }
            if (mkb) { vb = sgb; values_l[c1] = vb; marked_l[c1] = 0; }
            if (c0 == m2) { dead_l[m2] = 1; values_l[m2] = MAXD; indices_l[m2] = 0; va = MAXD; ia = 0; }
            if (c1 == m2) { dead_l[m2] = 1; values_l[m2] = MAXD; indices_l[m2] = 0; vb = MAXD; ib = 0; }
            const bool alA = !dda && (c0 != m2);
            const bool alB = !ddb && (c1 != m2);

            // staleness substitution (one-iteration window, rows/col pm1)
            float d1a = v1a.x, x1a = v1a.y, d1b = v1b.x, x1b = v1b.y;
            float d2a = v2a.x, x2a = v2a.y, d2b = v2b.x, x2b = v2b.y;
            if (h1) {
                d1a = newv_h[pb][c0]; x1a = crossv_h[pb][c0];
                d1b = newv_h[pb][c1]; x1b = crossv_h[pb][c1];
            } else {
                if (c0 == pm1) { d1a = newv_h[pb][m1]; x1a = crossv_h[pb][m1]; }
                if (c1 == pm1) { d1b = newv_h[pb][m1]; x1b = crossv_h[pb][m1]; }
            }
            if (h2) {
                d2a = newv_h[pb][c0]; x2a = crossv_h[pb][c0];
                d2b = newv_h[pb][c1]; x2b = crossv_h[pb][c1];
            } else {
                if (c0 == pm1) { d2a = newv_h[pb][m2]; x2a = crossv_h[pb][m2]; }
                if (c1 == pm1) { d2b = newv_h[pb][m2]; x2b = crossv_h[pb][m2]; }
            }

            // deferred label apply (prev iter's cut), then slot merge
            if (takeP && sla == pm1) label_l[c0] = labP;
            if (takeP && slb == pm1) label_l[c1] = labP;
            if (sla == m2) slot_l[c0] = m1;
            if (slb == m2) slot_l[c1] = m1;

            if (c0 == m2) s_cross12 = x1a;  // old cross(m1,m2), consumed post-B2
            if (c1 == m2) s_cross12 = x1b;

            float nva = MAXD, nxa = 0.0f, nvb = MAXD, nxb = 0.0f;
            if (alA && c0 != m1) {
                nva = __fdiv_rn(__fadd_rn(__fmul_rn(d1a, cs1), __fmul_rn(d2a, cs2)), ncs);
                nxa = x1a + x2a;
            }
            if (alB && c1 != m1) {
                nvb = __fdiv_rn(__fadd_rn(__fmul_rn(d1b, cs1), __fmul_rn(d2b, cs2)), ncs);
                nxb = x1b + x2b;
            }
            newv_h[cb][c0] = nva; crossv_h[cb][c0] = nxa;  // MAXD-fill for dead/m1
            newv_h[cb][c1] = nvb; crossv_h[cb][c1] = nxb;

            // incremental row-min maintenance, row c0
            if (c0 == m1) {
                values_l[c0] = MAXD;  // transient; wave1 stages the new min
                marked_l[c0] = 1;
            } else if (alA && va < MAXD) {
                if (ia == m2) {
                    rlist[cb][atomicAdd(&nrec[cb], 1)] = c0;
                    values_l[c0] = MAXD; marked_l[c0] = 1;
                } else if (ia == m1) {  // implies c0 < m1
                    if (nva <= va) values_l[c0] = nva;  // lowest-index tie preserved
                    else {
                        rlist[cb][atomicAdd(&nrec[cb], 1)] = c0;
                        values_l[c0] = MAXD; marked_l[c0] = 1;
                    }
                } else if (c0 < m1) {  // col m1 got nva in row c0
                    if (nva < va) { values_l[c0] = nva; indices_l[c0] = m1; }
                    else if (nva == va && m1 < ia) indices_l[c0] = m1;  // jnp tie-break
                }
            }
            // row c1
            if (c1 == m1) {
                values_l[c1] = MAXD;
                marked_l[c1] = 1;
            } else if (alB && vb < MAXD) {
                if (ib == m2) {
                    rlist[cb][atomicAdd(&nrec[cb], 1)] = c1;
                    values_l[c1] = MAXD; marked_l[c1] = 1;
                } else if (ib == m1) {  // implies c1 < m1
                    if (nvb <= vb) values_l[c1] = nvb;
                    else {
                        rlist[cb][atomicAdd(&nrec[cb], 1)] = c1;
                        values_l[c1] = MAXD; marked_l[c1] = 1;
                    }
                } else if (c1 < m1) {
                    if (nvb < vb) { values_l[c1] = nvb; indices_l[c1] = m1; }
                    else if (nvb == vb && m1 < ib) indices_l[c1] = m1;
                }
            }
        } else {
            // store waves: retire LAST iter's stores -> B2 is the visibility
            // fence for them. Overlaps compute waves' P2 entirely.
            asm volatile("s_waitcnt vmcnt(0)" ::: "memory");
        }
        barrier_lds_only();  // B2

        // ================= P3 =================
        const int n = nrec[cb];
        if (t == 0) nrec[pb] = 0;

        if (wid < 8) {
            if (c0 == m1 || c1 == m1) cs_l[m1] = ncs;  // unread during P3

            if (wid == 0) {
                if (lane == 0) {
                    // cut decision (f64 accumulators)
                    double merge_e = within_l[m1] + within_l[m2] + (double)s_cross12;
                    double e_sum = energy_l[m1] + energy_l[m2];
                    int take = (merge_e >= e_sum) ? 1 : 0;
                    within_l[m1] = merge_e;
                    energy_l[m1] = take ? merge_e : e_sum;
                    s_takeP = take;
                    s_m1P = m1;
                    s_labP = D + it;
                }
                // full argmin scan of values_l (marked rows are MAXD and stable)
                const float4* v4 = (const float4*)values_l;
                u64 bb = ~0ull;  // (val<<32)|row during reduce
#pragma unroll
                for (int c = 0; c < 4; ++c) {
                    int fi = lane + 64 * c;
                    float4 q = v4[fi];
                    int b = fi << 2;
                    u64 k;
                    k = ((u64)__float_as_uint(q.x) << 32) | (u32)(b + 0); if (k < bb) bb = k;
                    k = ((u64)__float_as_uint(q.y) << 32) | (u32)(b + 1); if (k < bb) bb = k;
                    k = ((u64)__float_as_uint(q.z) << 32) | (u32)(b + 2); if (k < bb) bb = k;
                    k = ((u64)__float_as_uint(q.w) << 32) | (u32)(b + 3); if (k < bb) bb = k;
                }
                for (int o = 32; o; o >>= 1) {
                    u64 k2 = __shfl_xor(bb, o);
                    if (k2 < bb) bb = k2;
                }
                if (lane == 0) {
                    int r = (int)(bb & 1023);
                    int idx2 = indices_l[r];  // r unmarked -> stable during P3
                    atomicMin(&s_best[pb],
                              (bb & 0xffffffff00000000ull) | ((u32)r << 10) | (u32)idx2);
                }
                // speculative prefetch of the candidate pair's rows (likely
                // next m1/m2): one dword per 64B line covers both 8KB rows.
                {
                    int r_pf = (int)(bb & 1023);
                    int i_pf = indices_l[r_pf];
                    const float* br = (const float*)(dc + (size_t)r_pf * D);
                    const float* bi = (const float*)(dc + (size_t)i_pf * D);
                    pf0 = br[lane * 16];
                    pf1 = br[1024 + lane * 16];
                    pf2 = bi[lane * 16];
                    pf3 = bi[1024 + lane * 16];
                }
            } else if (wid == 1) {
                // row m1's new min from LDS (dead cols are MAXD by construction)
                u64 bb = ((u64)MAXDb << 32);  // (val<<32)|col
                const float4* nv4 = (const float4*)newv_h[cb];
                for (int c = lane; c < D / 4; c += 64) {
                    float4 q = nv4[c];
                    int j0 = c << 2;
#pragma unroll
                    for (int e = 0; e < 4; ++e) {
                        int j = j0 + e;
                        float dv = (e == 0) ? q.x : (e == 1) ? q.y : (e == 2) ? q.z : q.w;
                        if (j > m1) {
                            u64 k = ((u64)__float_as_uint(dv) << 32) | (u32)j;
                            if (k < bb) bb = k;
                        }
                    }
                }
                for (int o = 32; o; o >>= 1) {
                    u64 k2 = __shfl_xor(bb, o);
                    if (k2 < bb) bb = k2;
                }
                if (lane == 0) {
                    values_stage[m1] = __uint_as_float((u32)(bb >> 32));
                    indices_l[m1] = (int)(bb & 0xffffffffu);
                    atomicMin(&s_best[pb],
                              (bb & 0xffffffff00000000ull) | ((u32)m1 << 10) | (bb & 1023));
                }
            } else {
                // residual rescans (argmin retired/rose), waves 2-7.
                // All stores from iters < it are visible (B2 fence); current
                // col m1 is substituted from LDS. Pure loads -> no vmcnt
                // coupling with any store.
                for (int q = wid - 2; q < n; q += 6) {
                    const int r = rlist[cb][q];
                    const float subst = newv_h[cb][r];  // col-m1 value in flight
                    const float4* row4 = (const float4*)(dc + (size_t)r * D);
                    const int cc0 = r >> 1;  // first float4 covering cols > r
                    int ci0 = cc0 + lane;       if (ci0 > 511) ci0 = 511;
                    int ci1 = cc0 + lane + 64;  if (ci1 > 511) ci1 = 511;
                    int ci2 = cc0 + lane + 128; if (ci2 > 511) ci2 = 511;
                    int ci3 = cc0 + lane + 192; if (ci3 > 511) ci3 = 511;
                    int ci4 = cc0 + lane + 256; if (ci4 > 511) ci4 = 511;
                    int ci5 = cc0 + lane + 320; if (ci5 > 511) ci5 = 511;
                    int ci6 = cc0 + lane + 384; if (ci6 > 511) ci6 = 511;
                    int ci7 = cc0 + lane + 448; if (ci7 > 511) ci7 = 511;
                    float4 a0 = row4[ci0];
                    float4 a1 = row4[ci1];
                    float4 a2 = row4[ci2];
                    float4 a3 = row4[ci3];
                    float4 a4 = row4[ci4];
                    float4 a5 = row4[ci5];
                    float4 a6 = row4[ci6];
                    float4 a7 = row4[ci7];
                    u64 bb = ((u64)MAXDb << 32);  // (val<<32)|col
#define ACC2(af, civ)                                                           \
                    {                                                           \
                        int j0 = (civ) << 1;                                    \
                        float dv0 = (j0 == m1) ? subst : (af).x;                \
                        if (j0 > r && !dead_l[j0]) {                            \
                            u64 k = ((u64)__float_as_uint(dv0) << 32) | (u32)j0;\
                            if (k < bb) bb = k;                                 \
                        }                                                       \
                        int j1 = j0 + 1;                                        \
                        float dv1 = (j1 == m1) ? subst : (af).z;                \
                        if (j1 > r && !dead_l[j1]) {                            \
                            u64 k = ((u64)__float_as_uint(dv1) << 32) | (u32)j1;\
                            if (k < bb) bb = k;                                 \
                        }                                                       \
                    }
                    ACC2(a0, ci0)
                    ACC2(a1, ci1)
                    ACC2(a2, ci2)
                    ACC2(a3, ci3)
                    ACC2(a4, ci4)
                    ACC2(a5, ci5)
                    ACC2(a6, ci6)
                    ACC2(a7, ci7)
#undef ACC2
                    for (int o = 32; o; o >>= 1) {
                        u64 k2 = __shfl_xor(bb, o);
                        if (k2 < bb) bb = k2;
                    }
                    if (lane == 0) {
                        values_stage[r] = __uint_as_float((u32)(bb >> 32));
                        indices_l[r] = (int)(bb & 0xffffffffu);
                        atomicMin(&s_best[pb],
                                  (bb & 0xffffffff00000000ull) | ((u32)r << 10) | (bb & 1023));
                    }
                }
            }
        } else {
            // store waves: all global stores for this merge, from LDS.
            // nv==MAXD <=> dead or diagonal -> skip (those entries are never
            // read unmasked). Drain is NOT waited on here -- it overlaps the
            // whole next iteration; retired at next P2's vmcnt(0).
            const float nva = newv_h[cb][c0], nxa = crossv_h[cb][c0];
            const float nvb = newv_h[cb][c1], nxb = crossv_h[cb][c1];
            if (nva != MAXD) {
                dc[(size_t)m1 * D + c0] = make_float2(nva, nxa);  // row (coalesced)
                dc[(size_t)c0 * D + m1] = make_float2(nva, nxa);  // col (scatter)
            }
            if (nvb != MAXD) {
                dc[(size_t)m1 * D + c1] = make_float2(nvb, nxb);
                dc[(size_t)c1 * D + m1] = make_float2(nvb, nxb);
            }
        }
        barrier_lds_only();  // B3: LDS-only -- no store drain on the barrier
        // keep the prefetch loads alive (wave0 has no outstanding stores)
        if (wid == 0) asm volatile("" :: "v"(pf0), "v"(pf1), "v"(pf2), "v"(pf3));
    }

    // apply the final iteration's deferred cut, then emit labels
    {
        int lab = label_l[t];
        if (s_takeP && slot_l[t] == s_m1P) lab = s_labP;
        labels_g[t] = lab;
    }
}

// ---------- kernel D: R[a][b] = (a==b) || (label[a]==label[b]) ----------
__global__ void k_out(const int* __restrict__ labels, float* __restrict__ out) {
    int idx = blockIdx.x * blockDim.x + threadIdx.x;
    if (idx >= D * D) return;
    int i = idx >> 10, j = idx & (D - 1);
    out[idx] = (i == j || labels[i] == labels[j]) ? 1.0f : 0.0f;
}

extern "C" void kernel_launch(void* const* d_in, const int* in_sizes, int n_in,
                              void* d_out, int out_size, void* d_ws, size_t ws_size,
                              hipStream_t stream) {
    const float* X = (const float*)d_in[0];
    const float* W = (const float*)d_in[1];

    char* ws = (char*)d_ws;
    const size_t MAT_BYTES = (size_t)D * D * sizeof(float);  // 4 MiB
    float2* dc = (float2*)ws;                                // 8 MiB interleaved
    float* values_g = (float*)(ws + 2 * MAT_BYTES);
    int* indices_g = (int*)(ws + 2 * MAT_BYTES + 4096);
    int* labels_g = (int*)(ws + 2 * MAT_BYTES + 8192);
    u32* scal = (u32*)(ws + 2 * MAT_BYTES + 12288);

    hipMemsetAsync(scal, 0, 2 * sizeof(u32), stream);
    k_maxred<<<256, 256, 0, stream>>>(X, scal);
    k_init<<<(D * D) / 256, 256, 0, stream>>>(X, W, dc, scal);
    k_rowmin<<<D, 64, 0, stream>>>(dc, values_g, indices_g, scal);
    k_hac<<<1, 1024, 0, stream>>>(dc, values_g, indices_g, labels_g, scal);
    k_out<<<(D * D) / 256, 256, 0, stream>>>(labels_g, (float*)d_out);
}

// Round 9
// 3566.032 us; speedup vs baseline: 1.1797x; 1.1797x over previous
//
#include <hip/hip_runtime.h>
#include <stdint.h>

#define D 1024

typedef unsigned long long u64;
typedef unsigned int u32;

// ---------- monotonic float<->uint mapping for atomic max ----------
__device__ __forceinline__ u32 enc_f(float f) {
    u32 b = __float_as_uint(f);
    return (b & 0x80000000u) ? ~b : (b | 0x80000000u);
}
__device__ __forceinline__ float dec_f(u32 u) {
    u32 b = (u & 0x80000000u) ? (u ^ 0x80000000u) : ~u;
    return __uint_as_float(b);
}

// ---------- kernel A: max(X), max|X| ----------
__global__ void k_maxred(const float* __restrict__ X, u32* scal) {
    float mx = -INFINITY, ma = 0.f;
    int stride = gridDim.x * blockDim.x;
    for (int i = blockIdx.x * blockDim.x + threadIdx.x; i < D * D; i += stride) {
        float v = X[i];
        mx = fmaxf(mx, v);
        ma = fmaxf(ma, fabsf(v));
    }
    for (int o = 32; o; o >>= 1) {
        mx = fmaxf(mx, __shfl_xor(mx, o));
        ma = fmaxf(ma, __shfl_xor(ma, o));
    }
    if ((threadIdx.x & 63) == 0) {
        atomicMax(&scal[0], enc_f(mx));  // max_sim
        atomicMax(&scal[1], enc_f(ma));  // max|X|
    }
}

// ---------- kernel B: init interleaved (dist, cross) float2 matrix ----------
__global__ void k_init(const float* __restrict__ X, const float* __restrict__ W,
                       float2* __restrict__ dc, const u32* __restrict__ scal) {
    int idx = blockIdx.x * blockDim.x + threadIdx.x;
    if (idx >= D * D) return;
    float max_sim = dec_f(scal[0]);
    float MAXD = __fmul_rn(dec_f(scal[1]), 1000.0f);
    int i = idx >> 10, j = idx & (D - 1);
    float x = X[idx];
    // X is bitwise symmetric (0.5*(A+A^T)), so this matches max_sim - X[min][max]
    float di = (i == j) ? MAXD : __fsub_rn(max_sim, x);
    float cx = (i == j) ? 0.0f : (W[idx] + W[j * D + i]);  // one addend is exactly 0
    dc[idx] = make_float2(di, cx);
}

// ---------- kernel B2: initial per-row (min,argmin) over upper triangle ----------
__global__ void k_rowmin(const float2* __restrict__ dc, float* __restrict__ values_g,
                         int* __restrict__ indices_g, const u32* __restrict__ scal) {
    int r = blockIdx.x;
    int lane = threadIdx.x;  // 64 threads = 1 wave
    float MAXD = __fmul_rn(dec_f(scal[1]), 1000.0f);
    u64 best = ((u64)__float_as_uint(MAXD) << 32);  // (MAXD, idx 0) like jnp.argmin on all-MAXD row
    const float4* row4 = (const float4*)(dc + (size_t)r * D);
    for (int c = lane; c < D / 2; c += 64) {
        float4 q = row4[c];
        int j0 = c << 1;
        if (j0 > r) {
            u64 k = ((u64)__float_as_uint(q.x) << 32) | (u32)j0;
            if (k < best) best = k;
        }
        if (j0 + 1 > r) {
            u64 k = ((u64)__float_as_uint(q.z) << 32) | (u32)(j0 + 1);
            if (k < best) best = k;
        }
    }
    for (int o = 32; o; o >>= 1) {
        u64 k2 = __shfl_xor(best, o);
        if (k2 < best) best = k2;
    }
    if (lane == 0) {
        values_g[r] = __uint_as_float((u32)(best >> 32));
        indices_g[r] = (int)(best & 0xffffffffu);
    }
}

// ---------- kernel C: persistent single-block HAC loop ----------
// Round-4 store policy (proven twice: overlapping the scattered col-store
// drain with loads costs more than the drain): stores issue inside P3 and
// drain at B3 (full __syncthreads) where no loads are pending.
// Thread-private HAC state (values, indices, marked, slot, label, own-dead)
// lives in REGISTERS -- external writes only touch marked rows, restored from
// values_stage/indices_l by the owner thread. Each thread holds its final
// (v, idx) at the end of P2, so the global argmin is published IN P2 via
// per-wave shuffle-reduce + one LDS atomicMin per wave. P3's serial full-scan
// is eliminated; P3 = cut decision, wave1 newv scan, rescans, col stores.
// Ordering: s_best[cb] reset lives in P3 (t0) -- B3 orders it before next
// P2's publishes; B2 orders P2 publishes before wave0's prefetch read.
// BOTH barriers are full __syncthreads() this round (the hand-rolled
// LDS-only B2 is the only untested interaction with the new publish protocol
// after round 8's crash -- re-introduce it only once this passes).
__global__ void __launch_bounds__(1024) k_hac(
        float2* __restrict__ dc,
        const float* __restrict__ values_g, const int* __restrict__ indices_g,
        int* __restrict__ labels_g, const u32* __restrict__ scal) {
    __shared__ float values_stage[D];   // P3 scan results (restored next P2)
    __shared__ int indices_l[D];        // written by wave1/rescans for marked rows
    __shared__ __align__(16) float newv_l[D];
    __shared__ float cs_l[D];
    __shared__ unsigned char dead_l[D]; // cross-thread reads in rescans
    __shared__ int rlist[2][D];
    __shared__ int nrec[2];
    __shared__ u64 s_best[2];   // double-buffered global-argmin accumulator
    __shared__ float s_cross12;
    __shared__ double within_l[D];
    __shared__ double energy_l[D];
    __shared__ int s_takeP, s_m1P, s_labP;  // deferred cut (applied next iter)

    const int t = threadIdx.x;
    const int lane = t & 63, wid = t >> 6;
    const float MAXD = __fmul_rn(dec_f(scal[1]), 1000.0f);
    const u32 MAXDb = __float_as_uint(MAXD);

    // ---- thread-private state in registers (loop-carried) ----
    float vreg = values_g[t];   // row t's maintained min
    int ireg = indices_g[t];    // row t's maintained argmin
    int mreg = 0;               // marked: restore from stage next P2
    int dreg = 0;               // own-dead flag
    int sreg = t;               // slot (leaf -> active cluster id)
    int lreg = t;               // label

    values_stage[t] = vreg;     // defensive init (restore path never reads junk)
    indices_l[t] = ireg;
    cs_l[t] = 1.0f;
    dead_l[t] = 0;
    within_l[t] = 0.0;
    energy_l[t] = 0.0;
    if (t == 0) {
        s_takeP = 0; s_m1P = -1; s_labP = 0;
        nrec[0] = 0; nrec[1] = 0;
        s_best[0] = ~0ull; s_best[1] = ~0ull;
    }
    __syncthreads();
    // boot publish: per-wave reduce -> atomicMin into s_best[0]
    {
        u64 key = ((u64)__float_as_uint(vreg) << 32) | ((u32)t << 10) | (u32)ireg;
        for (int o = 32; o; o >>= 1) {
            u64 k2 = __shfl_xor(key, o);
            if (k2 < key) key = k2;
        }
        if (lane == 0) atomicMin(&s_best[0], key);
    }
    __syncthreads();

    float pf0 = 0.f, pf1 = 0.f, pf2 = 0.f, pf3 = 0.f;  // prefetch sinks

    for (int it = 0; it < D - 1; ++it) {
        const int cb = it & 1, pb = cb ^ 1;

        // ================= P2 =================
        const u64 bk = s_best[cb];  // one LDS read -> m1 AND m2
        const int m1 = (int)((bk >> 10) & 1023);
        const int m2 = (int)(bk & 1023);

        // global row loads FIRST: unconditional, depend only on s_best.
        // (Likely L1/L2 hits when wave0's prefetch predicted correctly.)
        const float2 v1 = dc[(size_t)m1 * D + t];
        const float2 v2 = dc[(size_t)m2 * D + t];

        // hoisted independent LDS reads (issue in parallel, no chaining)
        const float cs1 = cs_l[m1], cs2 = cs_l[m2];
        const float v_stg = values_stage[t];
        const int i_stg = indices_l[t];
        const int pm1 = s_m1P;
        const int takeP = s_takeP, labP = s_labP;

        const float ncs = __fadd_rn(cs1, cs2);

        // restore staged P3 results (marked rows), then freeze m2
        if (mreg) { vreg = v_stg; ireg = i_stg; mreg = 0; }
        if (t == m2) {
            dreg = 1;
            dead_l[m2] = 1;
            vreg = MAXD;  // vmask freeze
            ireg = 0;     // argmin of all-MAXD row
        }
        const bool alive = !dreg;

        const float d1 = v1.x, c1 = v1.y, d2 = v2.x, c2 = v2.y;

        // deferred label apply (prev iter's cut), then slot merge
        if (takeP && sreg == pm1) lreg = labP;
        if (sreg == m2) sreg = m1;

        float nv = MAXD, ncx = 0.0f;
        bool do_st = false;
        if (t == m2) s_cross12 = c1;  // old cross(m1,m2), consumed post-B2
        if (alive && t != m1) {
            nv = __fdiv_rn(__fadd_rn(__fmul_rn(d1, cs1), __fmul_rn(d2, cs2)), ncs);
            ncx = c1 + c2;
            dc[(size_t)m1 * D + t] = make_float2(nv, ncx);  // row m1 (coalesced)
            do_st = true;                                   // col store deferred to P3
        }
        newv_l[t] = nv;  // MAXD-fill: wave1 scan needs no dead mask

        // incremental row-min maintenance (registers; thread t == row t)
        {
            const float v = vreg;
            if (t == m1) {
                vreg = MAXD;  // transient; wave1 stages the new min
                mreg = 1;
            } else if (alive && v < MAXD) {
                if (ireg == m2) {
                    rlist[cb][atomicAdd(&nrec[cb], 1)] = t;
                    vreg = MAXD; mreg = 1;
                } else if (ireg == m1) {  // implies t < m1
                    if (nv <= v) vreg = nv;  // lowest-index tie preserved
                    else {
                        rlist[cb][atomicAdd(&nrec[cb], 1)] = t;
                        vreg = MAXD; mreg = 1;
                    }
                } else if (t < m1) {  // col m1 got nv in row t
                    if (nv < v) { vreg = nv; ireg = m1; }
                    else if (nv == v && m1 < ireg) ireg = m1;  // jnp.argmin tie-break
                }
            }
        }
        // publish this thread's final key (marked/dead rows carry MAXD and
        // never win; their true keys come from wave1/rescan publishers in P3)
        {
            u64 key = ((u64)__float_as_uint(vreg) << 32) | ((u32)t << 10) | (u32)ireg;
            for (int o = 32; o; o >>= 1) {
                u64 k2 = __shfl_xor(key, o);
                if (k2 < key) key = k2;
            }
            if (lane == 0) atomicMin(&s_best[pb], key);
        }
        __syncthreads();  // B2

        // ================= P3 =================
        if (t == m1) cs_l[m1] = ncs;  // nobody reads cs_l[m1] in P3
        const int n = nrec[cb];
        if (t == 0) {
            nrec[pb] = 0;
            s_best[cb] = ~0ull;  // reset for NEXT iter's P2 publishers (B3-ordered)
        }

        if (wid == 0) {
            // col store early: wave0's remaining work is LDS-only
            if (do_st) dc[(size_t)t * D + m1] = make_float2(nv, ncx);
            if (lane == 0) {
                // cut decision (f64 accumulators)
                double merge_e = within_l[m1] + within_l[m2] + (double)s_cross12;
                double e_sum = energy_l[m1] + energy_l[m2];
                int take = (merge_e >= e_sum) ? 1 : 0;
                within_l[m1] = merge_e;
                energy_l[m1] = take ? merge_e : e_sum;
                s_takeP = take;
                s_m1P = m1;
                s_labP = D + it;
            }
            // speculative prefetch of the likely next (m1,m2): s_best[pb]
            // already holds all 16 P2 publishes (B2-ordered); wave1/rescan
            // publishers may still beat it -> harmless mispredict (any decode
            // is in-bounds). One dword per 64B line covers both 8KB rows;
            // values consumed by the asm sink after B3 where vmcnt is 0.
            {
                const u64 cand = s_best[pb];
                int r_pf = (int)((cand >> 10) & 1023);
                int i_pf = (int)(cand & 1023);
                const float* br = (const float*)(dc + (size_t)r_pf * D);
                const float* bi = (const float*)(dc + (size_t)i_pf * D);
                pf0 = br[lane * 16];
                pf1 = br[1024 + lane * 16];
                pf2 = bi[lane * 16];
                pf3 = bi[1024 + lane * 16];
            }
        } else if (wid == 1) {
            // col store early: wave1's scan is LDS-only, store drains under it
            if (do_st) dc[(size_t)t * D + m1] = make_float2(nv, ncx);
            // row m1's new min from LDS newv_l (dead cols are MAXD by construction)
            u64 bb = ((u64)MAXDb << 32);  // (val<<32)|col
            const float4* nv4 = (const float4*)newv_l;
            for (int c = lane; c < D / 4; c += 64) {
                float4 q = nv4[c];
                int j0 = c << 2;
#pragma unroll
                for (int e = 0; e < 4; ++e) {
                    int j = j0 + e;
                    float dv = (e == 0) ? q.x : (e == 1) ? q.y : (e == 2) ? q.z : q.w;
                    if (j > m1) {
                        u64 k = ((u64)__float_as_uint(dv) << 32) | (u32)j;
                        if (k < bb) bb = k;
                    }
                }
            }
            for (int o = 32; o; o >>= 1) {
                u64 k2 = __shfl_xor(bb, o);
                if (k2 < bb) bb = k2;
            }
            if (lane == 0) {
                values_stage[m1] = __uint_as_float((u32)(bb >> 32));
                indices_l[m1] = (int)(bb & 0xffffffffu);
                atomicMin(&s_best[pb],
                          (bb & 0xffffffff00000000ull) | ((u32)m1 << 10) | (bb & 1023));
            }
        } else {
            // residual rescans (argmin retired/rose), one wave per row.
            // Row loads issue BEFORE the col store: in-order vmcnt means a
            // store-first ordering would stall load consumption on the
            // scattered store's RFO latency.
            bool pend_st = do_st;
            for (int q = wid - 2; q < n; q += 14) {
                const int r = rlist[cb][q];
                const float subst = newv_l[r];  // col-m1 value (store in flight)
                const float4* row4 = (const float4*)(dc + (size_t)r * D);
                float4 a0 = row4[lane];
                float4 a1 = row4[lane + 64];
                float4 a2 = row4[lane + 128];
                float4 a3 = row4[lane + 192];
                float4 a4 = row4[lane + 256];
                float4 a5 = row4[lane + 320];
                float4 a6 = row4[lane + 384];
                float4 a7 = row4[lane + 448];
                if (pend_st) {  // issue after loads; drains under the reduce
                    dc[(size_t)t * D + m1] = make_float2(nv, ncx);
                    pend_st = false;
                }
                u64 bb = ((u64)MAXDb << 32);  // (val<<32)|col
#define ACC2(af, koff)                                                          \
                {                                                               \
                    int j0 = (lane + (koff)) << 1;                              \
                    float dv0 = (j0 == m1) ? subst : (af).x;                    \
                    if (j0 > r && !dead_l[j0]) {                                \
                        u64 k = ((u64)__float_as_uint(dv0) << 32) | (u32)j0;    \
                        if (k < bb) bb = k;                                     \
                    }                                                           \
                    int j1 = j0 + 1;                                            \
                    float dv1 = (j1 == m1) ? subst : (af).z;                    \
                    if (j1 > r && !dead_l[j1]) {                                \
                        u64 k = ((u64)__float_as_uint(dv1) << 32) | (u32)j1;    \
                        if (k < bb) bb = k;                                     \
                    }                                                           \
                }
                ACC2(a0, 0)
                ACC2(a1, 64)
                ACC2(a2, 128)
                ACC2(a3, 192)
                ACC2(a4, 256)
                ACC2(a5, 320)
                ACC2(a6, 384)
                ACC2(a7, 448)
#undef ACC2
                for (int o = 32; o; o >>= 1) {
                    u64 k2 = __shfl_xor(bb, o);
                    if (k2 < bb) bb = k2;
                }
                if (lane == 0) {
                    values_stage[r] = __uint_as_float((u32)(bb >> 32));
                    indices_l[r] = (int)(bb & 0xffffffffu);
                    atomicMin(&s_best[pb],
                              (bb & 0xffffffff00000000ull) | ((u32)r << 10) | (bb & 1023));
                }
            }
            if (pend_st) dc[(size_t)t * D + m1] = make_float2(nv, ncx);
        }
        __syncthreads();  // B3: full drain; all waves' stores retire in parallel
        // keep the prefetch loads alive; vmcnt already 0 here -> free
        if (wid == 0) asm volatile("" :: "v"(pf0), "v"(pf1), "v"(pf2), "v"(pf3));
    }

    // apply the final iteration's deferred cut, then emit labels
    {
        int lab = lreg;
        if (s_takeP && sreg == s_m1P) lab = s_labP;
        labels_g[t] = lab;
    }
}

// ---------- kernel D: R[a][b] = (a==b) || (label[a]==label[b]) ----------
__global__ void k_out(const int* __restrict__ labels, float* __restrict__ out) {
    int idx = blockIdx.x * blockDim.x + threadIdx.x;
    if (idx >= D * D) return;
    int i = idx >> 10, j = idx & (D - 1);
    out[idx] = (i == j || labels[i] == labels[j]) ? 1.0f : 0.0f;
}

extern "C" void kernel_launch(void* const* d_in, const int* in_sizes, int n_in,
                              void* d_out, int out_size, void* d_ws, size_t ws_size,
                              hipStream_t stream) {
    const float* X = (const float*)d_in[0];
    const float* W = (const float*)d_in[1];

    char* ws = (char*)d_ws;
    const size_t MAT_BYTES = (size_t)D * D * sizeof(float);  // 4 MiB
    float2* dc = (float2*)ws;                                // 8 MiB interleaved
    float* values_g = (float*)(ws + 2 * MAT_BYTES);
    int* indices_g = (int*)(ws + 2 * MAT_BYTES + 4096);
    int* labels_g = (int*)(ws + 2 * MAT_BYTES + 8192);
    u32* scal = (u32*)(ws + 2 * MAT_BYTES + 12288);

    hipMemsetAsync(scal, 0, 2 * sizeof(u32), stream);
    k_maxred<<<256, 256, 0, stream>>>(X, scal);
    k_init<<<(D * D) / 256, 256, 0, stream>>>(X, W, dc, scal);
    k_rowmin<<<D, 64, 0, stream>>>(dc, values_g, indices_g, scal);
    k_hac<<<1, 1024, 0, stream>>>(dc, values_g, indices_g, labels_g, scal);
    k_out<<<(D * D) / 256, 256, 0, stream>>>(labels_g, (float*)d_out);
}

// Round 10
// 3340.276 us; speedup vs baseline: 1.2594x; 1.0676x over previous
//
#include <hip/hip_runtime.h>
#include <stdint.h>

#define D 1024

typedef unsigned long long u64;
typedef unsigned int u32;

// ---------- monotonic float<->uint mapping for atomic max ----------
__device__ __forceinline__ u32 enc_f(float f) {
    u32 b = __float_as_uint(f);
    return (b & 0x80000000u) ? ~b : (b | 0x80000000u);
}
__device__ __forceinline__ float dec_f(u32 u) {
    u32 b = (u & 0x80000000u) ? (u ^ 0x80000000u) : ~u;
    return __uint_as_float(b);
}

// LDS-only barrier: synchronizes DS traffic but does NOT drain vmcnt.
// Used at B2 only (round-4 proven): the sole pending global store there is
// the coalesced row-m1 store, which has NO consumer inside P3 (rescans
// substitute col m1 from LDS and never read row m1; wave0/wave1 scan LDS
// only). It drains in the shadow of P3 and is retired at B3.
__device__ __forceinline__ void barrier_lds_only() {
    __builtin_amdgcn_sched_barrier(0);
    asm volatile("s_waitcnt lgkmcnt(0)" ::: "memory");
    __builtin_amdgcn_s_barrier();
    asm volatile("" ::: "memory");
    __builtin_amdgcn_sched_barrier(0);
}

// ---------- kernel A: max(X), max|X| ----------
__global__ void k_maxred(const float* __restrict__ X, u32* scal) {
    float mx = -INFINITY, ma = 0.f;
    int stride = gridDim.x * blockDim.x;
    for (int i = blockIdx.x * blockDim.x + threadIdx.x; i < D * D; i += stride) {
        float v = X[i];
        mx = fmaxf(mx, v);
        ma = fmaxf(ma, fabsf(v));
    }
    for (int o = 32; o; o >>= 1) {
        mx = fmaxf(mx, __shfl_xor(mx, o));
        ma = fmaxf(ma, __shfl_xor(ma, o));
    }
    if ((threadIdx.x & 63) == 0) {
        atomicMax(&scal[0], enc_f(mx));  // max_sim
        atomicMax(&scal[1], enc_f(ma));  // max|X|
    }
}

// ---------- kernel B: init interleaved (dist, cross) float2 matrix ----------
__global__ void k_init(const float* __restrict__ X, const float* __restrict__ W,
                       float2* __restrict__ dc, const u32* __restrict__ scal) {
    int idx = blockIdx.x * blockDim.x + threadIdx.x;
    if (idx >= D * D) return;
    float max_sim = dec_f(scal[0]);
    float MAXD = __fmul_rn(dec_f(scal[1]), 1000.0f);
    int i = idx >> 10, j = idx & (D - 1);
    float x = X[idx];
    // X is bitwise symmetric (0.5*(A+A^T)), so this matches max_sim - X[min][max]
    float di = (i == j) ? MAXD : __fsub_rn(max_sim, x);
    float cx = (i == j) ? 0.0f : (W[idx] + W[j * D + i]);  // one addend is exactly 0
    dc[idx] = make_float2(di, cx);
}

// ---------- kernel B2: initial per-row TOP-2 (min,argmin) over upper triangle ----------
__global__ void k_rowmin(const float2* __restrict__ dc,
                         float* __restrict__ values_g, int* __restrict__ indices_g,
                         float* __restrict__ values2_g, int* __restrict__ indices2_g,
                         const u32* __restrict__ scal) {
    int r = blockIdx.x;
    int lane = threadIdx.x;  // 64 threads = 1 wave
    float MAXD = __fmul_rn(dec_f(scal[1]), 1000.0f);
    const u32 MAXDb = __float_as_uint(MAXD);
    u64 b1 = ((u64)MAXDb << 32);            // (MAXD, idx 0) like jnp.argmin default
    u64 b2 = ((u64)MAXDb << 32) | 1023ull;  // invalid-by-value second
    const float4* row4 = (const float4*)(dc + (size_t)r * D);
    for (int c = lane; c < D / 2; c += 64) {
        float4 q = row4[c];
        int j0 = c << 1;
        if (j0 > r) {
            u64 k = ((u64)__float_as_uint(q.x) << 32) | (u32)j0;
            if (k < b1) { b2 = b1; b1 = k; } else if (k < b2) b2 = k;
        }
        if (j0 + 1 > r) {
            u64 k = ((u64)__float_as_uint(q.z) << 32) | (u32)(j0 + 1);
            if (k < b1) { b2 = b1; b1 = k; } else if (k < b2) b2 = k;
        }
    }
    for (int o = 32; o; o >>= 1) {
        u64 c1 = __shfl_xor(b1, o), c2 = __shfl_xor(b2, o);
        u64 lo = (b1 < c1) ? b1 : c1;
        u64 hi = (b1 < c1) ? c1 : b1;
        u64 mn2 = (b2 < c2) ? b2 : c2;
        u64 sec = (hi < mn2) ? hi : mn2;
        b1 = lo; b2 = sec;
    }
    if (lane == 0) {
        values_g[r] = __uint_as_float((u32)(b1 >> 32));
        indices_g[r] = (int)(b1 & 0xffffffffu);
        values2_g[r] = __uint_as_float((u32)(b2 >> 32));
        indices2_g[r] = (int)(b2 & 0xffffffffu);
    }
}

// ---------- kernel C: persistent single-block HAC loop ----------
// Round-4 structure (B2 LDS-only, stores drain at B3 full-sync, early
// unconditional row loads, wave0 speculative prefetch) + exact TOP-2
// second-min tracking per row (registers, owner-thread). When a row's argmin
// dies/rises, promote (v2,i2) in place instead of rescanning -- exact,
// tie-break-preserving (u64 key = valbits||idx, lowest index on ties); any
// case not provably exact (second invalid/dead/modified-up, ties through an
// unknown third) falls back to rescan. Rescans and wave1 now stage top-2.
// INVARIANT used by promotes: any column not in the tracked top-2 has
// key >= key(v2,i2); the second's validity is revoked whenever its column
// dies or its value changes non-provably.
__global__ void __launch_bounds__(1024) k_hac(
        float2* __restrict__ dc,
        const float* __restrict__ values_g, const int* __restrict__ indices_g,
        const float* __restrict__ values2_g, const int* __restrict__ indices2_g,
        int* __restrict__ labels_g, const u32* __restrict__ scal) {
    __shared__ __align__(16) float values_l[D];
    __shared__ float values_stage[D];   // P3 scan results (restored next P2)
    __shared__ float stage2_v[D];       // P3 second-min stage
    __shared__ int stage2_i[D];
    __shared__ int indices_l[D];
    __shared__ __align__(16) float newv_l[D];
    __shared__ float cs_l[D];
    __shared__ unsigned char dead_l[D];
    __shared__ unsigned char marked_l[D];  // row staged in P3 -> restore next P2
    __shared__ int slot_l[D];   // leaf -> active slot id
    __shared__ int label_l[D];
    __shared__ double within_l[D];
    __shared__ double energy_l[D];
    __shared__ int rlist[2][D];
    __shared__ int nrec[2];
    __shared__ u64 s_best[2];   // double-buffered global-argmin accumulator
    __shared__ float s_cross12;
    __shared__ int s_takeP, s_m1P, s_labP;  // deferred cut (applied next iter)

    const int t = threadIdx.x;
    const int lane = t & 63, wid = t >> 6;
    const float MAXD = __fmul_rn(dec_f(scal[1]), 1000.0f);
    const u32 MAXDb = __float_as_uint(MAXD);

    // second-min in registers (owner-thread only; staged via stage2_* in P3)
    float v2reg = values2_g[t];
    int i2reg = indices2_g[t];

    values_l[t] = values_g[t];
    indices_l[t] = indices_g[t];
    values_stage[t] = values_l[t];  // defensive
    stage2_v[t] = v2reg;            // defensive
    stage2_i[t] = i2reg;
    cs_l[t] = 1.0f;
    dead_l[t] = 0;
    marked_l[t] = 0;
    slot_l[t] = t;
    label_l[t] = t;
    within_l[t] = 0.0;
    energy_l[t] = 0.0;
    if (t == 0) {
        s_takeP = 0; s_m1P = -1; s_labP = 0;
        nrec[0] = 0; nrec[1] = 0;
        s_best[0] = ~0ull; s_best[1] = ~0ull;
    }
    __syncthreads();
    // boot publish: per-wave reduce over own 64 rows -> atomicMin into s_best[0]
    {
        u64 key = ((u64)__float_as_uint(values_l[t]) << 32) | ((u32)t << 10) |
                  (u32)indices_l[t];
        for (int o = 32; o; o >>= 1) {
            u64 k2 = __shfl_xor(key, o);
            if (k2 < key) key = k2;
        }
        if (lane == 0) atomicMin(&s_best[0], key);
    }
    __syncthreads();

    float pf0 = 0.f, pf1 = 0.f, pf2 = 0.f, pf3 = 0.f;  // prefetch sinks

    for (int it = 0; it < D - 1; ++it) {
        const int cb = it & 1, pb = cb ^ 1;

        // ================= P2 =================
        const u64 bk = s_best[cb];  // one LDS read -> m1 AND m2
        const int m1 = (int)((bk >> 10) & 1023);
        const int m2 = (int)(bk & 1023);

        // global row loads FIRST: unconditional, depend only on s_best.
        const float2 v1 = dc[(size_t)m1 * D + t];
        const float2 v2g = dc[(size_t)m2 * D + t];

        // hoisted independent LDS reads -- all issue in parallel
        const float cs1 = cs_l[m1], cs2 = cs_l[m2];
        const float v_std = values_l[t];
        const float v_stg = values_stage[t];
        const float s2v = stage2_v[t];
        const int s2i = stage2_i[t];
        const int mk = marked_l[t];
        const int dd = dead_l[t];
        int idx = indices_l[t];
        const int sl = slot_l[t];
        const int pm1 = s_m1P;
        const int takeP = s_takeP, labP = s_labP;
        if (t == 0) s_best[pb] = ~0ull;  // reset for this iter's publishers

        const float ncs = __fadd_rn(cs1, cs2);

        // restore staged P3 results (value + second), then freeze m2
        float v = mk ? v_stg : v_std;
        if (mk) { values_l[t] = v; marked_l[t] = 0; v2reg = s2v; i2reg = s2i; }
        if (t == m2) {
            dead_l[m2] = 1;
            values_l[m2] = MAXD;  // vmask freeze
            indices_l[m2] = 0;    // argmin of all-MAXD row
            v = MAXD;
            idx = 0;
        }
        const bool alive = !dd && (t != m2);

        const float d1 = v1.x, c1 = v1.y, d2 = v2g.x, c2 = v2g.y;

        // deferred label apply (prev iter's cut), then slot merge
        if (takeP && sl == pm1) label_l[t] = labP;
        if (sl == m2) slot_l[t] = m1;

        float nv = MAXD, ncx = 0.0f;
        bool do_st = false;
        if (t == m2) s_cross12 = c1;  // old cross(m1,m2), consumed post-B2
        if (alive && t != m1) {
            nv = __fdiv_rn(__fadd_rn(__fmul_rn(d1, cs1), __fmul_rn(d2, cs2)), ncs);
            ncx = c1 + c2;
            dc[(size_t)m1 * D + t] = make_float2(nv, ncx);  // row m1 (coalesced)
            do_st = true;                                   // col store deferred to P3
        }
        newv_l[t] = nv;  // MAXD-fill: wave1 scan needs no dead mask

        // ---- incremental TOP-2 row-min maintenance (thread t == row t) ----
        if (t == m1) {
            values_l[t] = MAXD;  // transient; wave1 stages the new top-2
            marked_l[t] = 1;
        } else if (alive && v < MAXD) {
            if (v2reg < MAXD && i2reg == m2) v2reg = MAXD;  // second died
            const bool v2ok = (v2reg < MAXD);
            const u64 kn = ((u64)__float_as_uint(nv) << 32) | (u32)m1;
            const u64 kv2 = ((u64)__float_as_uint(v2reg) << 32) | (u32)i2reg;
            bool resc = false;
            if (idx == m2) {
                // argmin died
                if (!v2ok) resc = true;
                else if (i2reg == m1) {  // second's col just changed (t < m1)
                    if (nv < v2reg) { values_l[t] = nv; indices_l[t] = m1; v2reg = MAXD; }
                    else resc = true;    // tie/raise through unknown third
                } else if (t < m1) {
                    if (kn < kv2) { values_l[t] = nv; indices_l[t] = m1; }  // v2 stays exact
                    else { values_l[t] = v2reg; indices_l[t] = i2reg; v2reg = MAXD; }
                } else {
                    values_l[t] = v2reg; indices_l[t] = i2reg; v2reg = MAXD;
                }
            } else if (idx == m1) {  // argmin col's value replaced (t < m1)
                if (nv <= v) {
                    values_l[t] = nv;  // same col, lowest-index tie preserved; v2 exact
                } else if (v2ok) {     // i2 != m1 here (i1 == m1)
                    if (kn < kv2) values_l[t] = nv;  // idx stays m1; v2 stays exact
                    else { values_l[t] = v2reg; indices_l[t] = i2reg; v2reg = MAXD; }
                } else resc = true;
            } else if (t < m1) {  // col m1 changed; argmin elsewhere
                const u64 kv1 = ((u64)__float_as_uint(v) << 32) | (u32)idx;
                if (kn < kv1) {
                    values_l[t] = nv; indices_l[t] = m1;
                    v2reg = v; i2reg = idx;  // old min is the exact new second
                } else if (v2ok) {
                    if (i2reg == m1) {
                        if (nv <= v2reg) v2reg = nv;  // same col, exact
                        else v2reg = MAXD;            // raised past unknown third
                    } else if (kn < kv2) { v2reg = nv; i2reg = m1; }
                    // else: top-2 unchanged (untracked cols >= v2 incl. old m1)
                }
                // v2 invalid && kn >= kv1: stays invalid
            }
            // t > m1 with uninvolved argmin: nothing changes in row range
            if (resc) {
                rlist[cb][atomicAdd(&nrec[cb], 1)] = t;
                values_l[t] = MAXD;
                marked_l[t] = 1;
            }
        }
        barrier_lds_only();  // B2: LDS-only; row-m1 store drains under P3

        // ================= P3 =================
        if (t == m1) cs_l[m1] = ncs;  // nobody reads cs_l[m1] in P3
        const int n = nrec[cb];
        if (t == 0) nrec[pb] = 0;

        if (wid == 0) {
            // col store early: wave0's scan is LDS-only, store drains under it
            if (do_st) dc[(size_t)t * D + m1] = make_float2(nv, ncx);
            if (lane == 0) {
                // cut decision (f64 accumulators)
                double merge_e = within_l[m1] + within_l[m2] + (double)s_cross12;
                double e_sum = energy_l[m1] + energy_l[m2];
                int take = (merge_e >= e_sum) ? 1 : 0;
                within_l[m1] = merge_e;
                energy_l[m1] = take ? merge_e : e_sum;
                s_takeP = take;
                s_m1P = m1;
                s_labP = D + it;
            }
            // full argmin scan of values_l (marked rows are MAXD and stable;
            // their true keys come from wave1/rescan publishers)
            const float4* v4 = (const float4*)values_l;
            u64 bb = ~0ull;  // (val<<32)|row during reduce
#pragma unroll
            for (int c = 0; c < 4; ++c) {
                int fi = lane + 64 * c;
                float4 q = v4[fi];
                int b = fi << 2;
                u64 k;
                k = ((u64)__float_as_uint(q.x) << 32) | (u32)(b + 0); if (k < bb) bb = k;
                k = ((u64)__float_as_uint(q.y) << 32) | (u32)(b + 1); if (k < bb) bb = k;
                k = ((u64)__float_as_uint(q.z) << 32) | (u32)(b + 2); if (k < bb) bb = k;
                k = ((u64)__float_as_uint(q.w) << 32) | (u32)(b + 3); if (k < bb) bb = k;
            }
            for (int o = 32; o; o >>= 1) {
                u64 k2 = __shfl_xor(bb, o);
                if (k2 < bb) bb = k2;
            }
            if (lane == 0) {
                int r = (int)(bb & 1023);
                int idx2 = indices_l[r];  // r is unmarked -> stable during P3
                atomicMin(&s_best[pb],
                          (bb & 0xffffffff00000000ull) | ((u32)r << 10) | (u32)idx2);
            }
            // speculative prefetch of the candidate pair's rows (likely next
            // m1/m2). One dword per 64B segment covers every cache line of
            // both 8KB rows. Consumed by the asm sink after B3 (vmcnt==0).
            {
                int r_pf = (int)(bb & 1023);
                int i_pf = indices_l[r_pf];
                const float* br = (const float*)(dc + (size_t)r_pf * D);
                const float* bi = (const float*)(dc + (size_t)i_pf * D);
                pf0 = br[lane * 16];
                pf1 = br[1024 + lane * 16];
                pf2 = bi[lane * 16];
                pf3 = bi[1024 + lane * 16];
            }
        } else if (wid == 1) {
            // col store early: wave1's scan is LDS-only, store drains under it
            if (do_st) dc[(size_t)t * D + m1] = make_float2(nv, ncx);
            // row m1's new TOP-2 from LDS newv_l (dead cols are MAXD)
            u64 b1 = ((u64)MAXDb << 32);
            u64 b2 = ((u64)MAXDb << 32) | 1023ull;
            const float4* nv4 = (const float4*)newv_l;
            for (int c = lane; c < D / 4; c += 64) {
                float4 q = nv4[c];
                int j0 = c << 2;
#pragma unroll
                for (int e = 0; e < 4; ++e) {
                    int j = j0 + e;
                    float dv = (e == 0) ? q.x : (e == 1) ? q.y : (e == 2) ? q.z : q.w;
                    if (j > m1) {
                        u64 k = ((u64)__float_as_uint(dv) << 32) | (u32)j;
                        if (k < b1) { b2 = b1; b1 = k; } else if (k < b2) b2 = k;
                    }
                }
            }
            for (int o = 32; o; o >>= 1) {
                u64 c1k = __shfl_xor(b1, o), c2k = __shfl_xor(b2, o);
                u64 lo = (b1 < c1k) ? b1 : c1k;
                u64 hi = (b1 < c1k) ? c1k : b1;
                u64 mn2 = (b2 < c2k) ? b2 : c2k;
                u64 sec = (hi < mn2) ? hi : mn2;
                b1 = lo; b2 = sec;
            }
            if (lane == 0) {
                values_stage[m1] = __uint_as_float((u32)(b1 >> 32));
                indices_l[m1] = (int)(b1 & 0xffffffffu);
                stage2_v[m1] = __uint_as_float((u32)(b2 >> 32));
                stage2_i[m1] = (int)(b2 & 0xffffffffu);
                atomicMin(&s_best[pb],
                          (b1 & 0xffffffff00000000ull) | ((u32)m1 << 10) | (b1 & 1023));
            }
        } else {
            // residual rescans (exactness fallback), one wave per row.
            // Row loads issue BEFORE the col store (in-order vmcnt).
            bool pend_st = do_st;
            for (int q = wid - 2; q < n; q += 14) {
                const int r = rlist[cb][q];
                const float subst = newv_l[r];  // col-m1 value (store in flight)
                const float4* row4 = (const float4*)(dc + (size_t)r * D);
                float4 a0 = row4[lane];
                float4 a1 = row4[lane + 64];
                float4 a2 = row4[lane + 128];
                float4 a3 = row4[lane + 192];
                float4 a4 = row4[lane + 256];
                float4 a5 = row4[lane + 320];
                float4 a6 = row4[lane + 384];
                float4 a7 = row4[lane + 448];
                if (pend_st) {  // issue after loads; drains under the reduce
                    dc[(size_t)t * D + m1] = make_float2(nv, ncx);
                    pend_st = false;
                }
                u64 b1 = ((u64)MAXDb << 32);
                u64 b2 = ((u64)MAXDb << 32) | 1023ull;
#define ACC2(af, koff)                                                          \
                {                                                               \
                    int j0 = (lane + (koff)) << 1;                              \
                    float dv0 = (j0 == m1) ? subst : (af).x;                    \
                    if (j0 > r && !dead_l[j0]) {                                \
                        u64 k = ((u64)__float_as_uint(dv0) << 32) | (u32)j0;    \
                        if (k < b1) { b2 = b1; b1 = k; } else if (k < b2) b2 = k;\
                    }                                                           \
                    int j1 = j0 + 1;                                            \
                    float dv1 = (j1 == m1) ? subst : (af).z;                    \
                    if (j1 > r && !dead_l[j1]) {                                \
                        u64 k = ((u64)__float_as_uint(dv1) << 32) | (u32)j1;    \
                        if (k < b1) { b2 = b1; b1 = k; } else if (k < b2) b2 = k;\
                    }                                                           \
                }
                ACC2(a0, 0)
                ACC2(a1, 64)
                ACC2(a2, 128)
                ACC2(a3, 192)
                ACC2(a4, 256)
                ACC2(a5, 320)
                ACC2(a6, 384)
                ACC2(a7, 448)
#undef ACC2
                for (int o = 32; o; o >>= 1) {
                    u64 c1k = __shfl_xor(b1, o), c2k = __shfl_xor(b2, o);
                    u64 lo = (b1 < c1k) ? b1 : c1k;
                    u64 hi = (b1 < c1k) ? c1k : b1;
                    u64 mn2 = (b2 < c2k) ? b2 : c2k;
                    u64 sec = (hi < mn2) ? hi : mn2;
                    b1 = lo; b2 = sec;
                }
                if (lane == 0) {
                    values_stage[r] = __uint_as_float((u32)(b1 >> 32));
                    indices_l[r] = (int)(b1 & 0xffffffffu);
                    stage2_v[r] = __uint_as_float((u32)(b2 >> 32));
                    stage2_i[r] = (int)(b2 & 0xffffffffu);
                    atomicMin(&s_best[pb],
                              (b1 & 0xffffffff00000000ull) | ((u32)r << 10) | (b1 & 1023));
                }
            }
            if (pend_st) dc[(size_t)t * D + m1] = make_float2(nv, ncx);
        }
        __syncthreads();  // B3: full drain; all waves' stores retire in parallel
        // keep the prefetch loads alive; vmcnt already 0 here -> free
        if (wid == 0) asm volatile("" :: "v"(pf0), "v"(pf1), "v"(pf2), "v"(pf3));
    }

    // apply the final iteration's deferred cut, then emit labels
    {
        int lab = label_l[t];
        if (s_takeP && slot_l[t] == s_m1P) lab = s_labP;
        labels_g[t] = lab;
    }
}

// ---------- kernel D: R[a][b] = (a==b) || (label[a]==label[b]) ----------
__global__ void k_out(const int* __restrict__ labels, float* __restrict__ out) {
    int idx = blockIdx.x * blockDim.x + threadIdx.x;
    if (idx >= D * D) return;
    int i = idx >> 10, j = idx & (D - 1);
    out[idx] = (i == j || labels[i] == labels[j]) ? 1.0f : 0.0f;
}

extern "C" void kernel_launch(void* const* d_in, const int* in_sizes, int n_in,
                              void* d_out, int out_size, void* d_ws, size_t ws_size,
                              hipStream_t stream) {
    const float* X = (const float*)d_in[0];
    const float* W = (const float*)d_in[1];

    char* ws = (char*)d_ws;
    const size_t MAT_BYTES = (size_t)D * D * sizeof(float);  // 4 MiB
    float2* dc = (float2*)ws;                                // 8 MiB interleaved
    float* values_g = (float*)(ws + 2 * MAT_BYTES);
    int* indices_g = (int*)(ws + 2 * MAT_BYTES + 4096);
    int* labels_g = (int*)(ws + 2 * MAT_BYTES + 8192);
    u32* scal = (u32*)(ws + 2 * MAT_BYTES + 12288);
    float* values2_g = (float*)(ws + 2 * MAT_BYTES + 16384);
    int* indices2_g = (int*)(ws + 2 * MAT_BYTES + 20480);

    hipMemsetAsync(scal, 0, 2 * sizeof(u32), stream);
    k_maxred<<<256, 256, 0, stream>>>(X, scal);
    k_init<<<(D * D) / 256, 256, 0, stream>>>(X, W, dc, scal);
    k_rowmin<<<D, 64, 0, stream>>>(dc, values_g, indices_g, values2_g, indices2_g, scal);
    k_hac<<<1, 1024, 0, stream>>>(dc, values_g, indices_g, values2_g, indices2_g,
                                  labels_g, scal);
    k_out<<<(D * D) / 256, 256, 0, stream>>>(labels_g, (float*)d_out);
}

// Round 11
// 3062.756 us; speedup vs baseline: 1.3735x; 1.0906x over previous
//
#include <hip/hip_runtime.h>
#include <stdint.h>

#define D 1024

typedef unsigned long long u64;
typedef unsigned int u32;

// ---------- monotonic float<->uint mapping for atomic max ----------
__device__ __forceinline__ u32 enc_f(float f) {
    u32 b = __float_as_uint(f);
    return (b & 0x80000000u) ? ~b : (b | 0x80000000u);
}
__device__ __forceinline__ float dec_f(u32 u) {
    u32 b = (u & 0x80000000u) ? (u ^ 0x80000000u) : ~u;
    return __uint_as_float(b);
}

// LDS-only barrier: synchronizes DS traffic but does NOT drain vmcnt.
// Used at B2 only: the sole pending global store there is the coalesced
// row-m1 store, which has NO consumer inside P3 (rescans substitute col m1
// from LDS and never read row m1; wave0/wave1 scan LDS only). It drains
// in the shadow of P3 and is retired by the full __syncthreads() at B3.
__device__ __forceinline__ void barrier_lds_only() {
    __builtin_amdgcn_sched_barrier(0);
    asm volatile("s_waitcnt lgkmcnt(0)" ::: "memory");
    __builtin_amdgcn_s_barrier();
    asm volatile("" ::: "memory");
    __builtin_amdgcn_sched_barrier(0);
}

// ---------- kernel A: max(X), max|X| ----------
__global__ void k_maxred(const float* __restrict__ X, u32* scal) {
    float mx = -INFINITY, ma = 0.f;
    int stride = gridDim.x * blockDim.x;
    for (int i = blockIdx.x * blockDim.x + threadIdx.x; i < D * D; i += stride) {
        float v = X[i];
        mx = fmaxf(mx, v);
        ma = fmaxf(ma, fabsf(v));
    }
    for (int o = 32; o; o >>= 1) {
        mx = fmaxf(mx, __shfl_xor(mx, o));
        ma = fmaxf(ma, __shfl_xor(ma, o));
    }
    if ((threadIdx.x & 63) == 0) {
        atomicMax(&scal[0], enc_f(mx));  // max_sim
        atomicMax(&scal[1], enc_f(ma));  // max|X|
    }
}

// ---------- kernel B: init interleaved (dist, cross) float2 matrix ----------
__global__ void k_init(const float* __restrict__ X, const float* __restrict__ W,
                       float2* __restrict__ dc, const u32* __restrict__ scal) {
    int idx = blockIdx.x * blockDim.x + threadIdx.x;
    if (idx >= D * D) return;
    float max_sim = dec_f(scal[0]);
    float MAXD = __fmul_rn(dec_f(scal[1]), 1000.0f);
    int i = idx >> 10, j = idx & (D - 1);
    float x = X[idx];
    // X is bitwise symmetric (0.5*(A+A^T)), so this matches max_sim - X[min][max]
    float di = (i == j) ? MAXD : __fsub_rn(max_sim, x);
    float cx = (i == j) ? 0.0f : (W[idx] + W[j * D + i]);  // one addend is exactly 0
    dc[idx] = make_float2(di, cx);
}

// ---------- kernel B2: initial per-row (min,argmin) over upper triangle ----------
__global__ void k_rowmin(const float2* __restrict__ dc, float* __restrict__ values_g,
                         int* __restrict__ indices_g, const u32* __restrict__ scal) {
    int r = blockIdx.x;
    int lane = threadIdx.x;  // 64 threads = 1 wave
    float MAXD = __fmul_rn(dec_f(scal[1]), 1000.0f);
    u64 best = ((u64)__float_as_uint(MAXD) << 32);  // (MAXD, idx 0) like jnp.argmin on all-MAXD row
    const float4* row4 = (const float4*)(dc + (size_t)r * D);
    for (int c = lane; c < D / 2; c += 64) {
        float4 q = row4[c];
        int j0 = c << 1;
        if (j0 > r) {
            u64 k = ((u64)__float_as_uint(q.x) << 32) | (u32)j0;
            if (k < best) best = k;
        }
        if (j0 + 1 > r) {
            u64 k = ((u64)__float_as_uint(q.z) << 32) | (u32)(j0 + 1);
            if (k < best) best = k;
        }
    }
    for (int o = 32; o; o >>= 1) {
        u64 k2 = __shfl_xor(best, o);
        if (k2 < best) best = k2;
    }
    if (lane == 0) {
        values_g[r] = __uint_as_float((u32)(best >> 32));
        indices_g[r] = (int)(best & 0xffffffffu);
    }
}

// ---------- kernel C: persistent single-block HAC loop ----------
// Exact round-4 structure (best measured: 2962 us). dist/cross interleaved as
// float2. B2 is LDS-only (row-m1 store drains under P3, retired at B3). B3 is
// a full __syncthreads(): all 16 waves' scattered col stores drain in
// PARALLEL there. Rescan waves issue their row loads BEFORE the col store
// (in-order vmcnt retirement). P2 row loads are UNCONDITIONAL and issued
// immediately after decoding m1/m2.
// Prefetch covers BOTH likely winners now:
//   wave0: its argmin candidate pair (best standing row + partner)  [r4]
//   wave1: the freshly merged row's pair (m1, j* = its new argmin) [NEW] --
//          covers the common case where the merged cluster wins the argmin
//          (average-linkage: new dists are weighted means of two small vals).
// Both prefetches are one dword per 64B line, sunk after B3 (vmcnt==0 there).
__global__ void __launch_bounds__(1024) k_hac(
        float2* __restrict__ dc,
        const float* __restrict__ values_g, const int* __restrict__ indices_g,
        int* __restrict__ labels_g, const u32* __restrict__ scal) {
    __shared__ __align__(16) float values_l[D];
    __shared__ float values_stage[D];   // P3 scan results (restored next P2)
    __shared__ int indices_l[D];
    __shared__ __align__(16) float newv_l[D];
    __shared__ float cs_l[D];
    __shared__ unsigned char dead_l[D];
    __shared__ unsigned char marked_l[D];  // row staged in P3 -> restore next P2
    __shared__ int slot_l[D];   // leaf -> active slot id
    __shared__ int label_l[D];
    __shared__ double within_l[D];
    __shared__ double energy_l[D];
    __shared__ int rlist[2][D];
    __shared__ int nrec[2];
    __shared__ u64 s_best[2];   // double-buffered global-argmin accumulator
    __shared__ float s_cross12;
    __shared__ int s_takeP, s_m1P, s_labP;  // deferred cut (applied next iter)

    const int t = threadIdx.x;
    const int lane = t & 63, wid = t >> 6;
    const float MAXD = __fmul_rn(dec_f(scal[1]), 1000.0f);
    const u32 MAXDb = __float_as_uint(MAXD);

    values_l[t] = values_g[t];
    indices_l[t] = indices_g[t];
    cs_l[t] = 1.0f;
    dead_l[t] = 0;
    marked_l[t] = 0;
    slot_l[t] = t;
    label_l[t] = t;
    within_l[t] = 0.0;
    energy_l[t] = 0.0;
    if (t == 0) {
        s_takeP = 0; s_m1P = -1; s_labP = 0;
        nrec[0] = 0; nrec[1] = 0;
        s_best[0] = ~0ull; s_best[1] = ~0ull;
    }
    __syncthreads();
    // boot publish: per-wave reduce over own 64 rows -> atomicMin into s_best[0]
    {
        u64 key = ((u64)__float_as_uint(values_l[t]) << 32) | ((u32)t << 10) |
                  (u32)indices_l[t];
        for (int o = 32; o; o >>= 1) {
            u64 k2 = __shfl_xor(key, o);
            if (k2 < key) key = k2;
        }
        if (lane == 0) atomicMin(&s_best[0], key);
    }
    __syncthreads();

    float pf0 = 0.f, pf1 = 0.f, pf2 = 0.f, pf3 = 0.f;  // prefetch sinks

    for (int it = 0; it < D - 1; ++it) {
        const int cb = it & 1, pb = cb ^ 1;

        // ================= P2 =================
        const u64 bk = s_best[cb];  // one LDS read -> m1 AND m2
        const int m1 = (int)((bk >> 10) & 1023);
        const int m2 = (int)(bk & 1023);

        // row loads FIRST: unconditional, no LDS dependency beyond s_best.
        // (Likely L1/L2 hits when wave0/wave1's prefetch predicted correctly.)
        const float2 v1 = dc[(size_t)m1 * D + t];
        const float2 v2 = dc[(size_t)m2 * D + t];

        const float cs1 = cs_l[m1], cs2 = cs_l[m2];
        const float ncs = __fadd_rn(cs1, cs2);
        const int pm1 = s_m1P;
        const int takeP = s_takeP, labP = s_labP;
        if (t == 0) s_best[pb] = ~0ull;  // reset for this iter's publishers

        // restore staged P3 results, then freeze m2 (own-thread writes only)
        if (marked_l[t]) { values_l[t] = values_stage[t]; marked_l[t] = 0; }
        if (t == m2) {
            dead_l[m2] = 1;
            values_l[m2] = MAXD;  // vmask freeze
            indices_l[m2] = 0;    // argmin of all-MAXD row
        }
        const bool alive = !dead_l[t];

        const float d1 = v1.x, c1 = v1.y, d2 = v2.x, c2 = v2.y;

        // deferred label apply (prev iter's cut), then slot merge
        {
            int sl = slot_l[t];
            if (takeP && sl == pm1) label_l[t] = labP;
            if (sl == m2) slot_l[t] = m1;
        }

        float nv = MAXD, ncx = 0.0f;
        bool do_st = false;
        if (t == m2) s_cross12 = c1;  // old cross(m1,m2), consumed post-B2
        if (alive && t != m1) {
            nv = __fdiv_rn(__fadd_rn(__fmul_rn(d1, cs1), __fmul_rn(d2, cs2)), ncs);
            ncx = c1 + c2;
            dc[(size_t)m1 * D + t] = make_float2(nv, ncx);  // row m1 (coalesced)
            do_st = true;                                   // col store deferred to P3
        }
        newv_l[t] = nv;  // MAXD-fill: wave1 scan needs no dead mask

        // incremental row-min maintenance (thread t == row t)
        {
            float v = values_l[t];
            if (t == m1) {
                values_l[t] = MAXD;  // transient; wave1 stages the new min
                marked_l[t] = 1;
            } else if (alive && v < MAXD) {
                int idx = indices_l[t];
                if (idx == m2) {
                    rlist[cb][atomicAdd(&nrec[cb], 1)] = t;
                    values_l[t] = MAXD;
                    marked_l[t] = 1;
                } else if (idx == m1) {  // implies t < m1
                    if (nv <= v) values_l[t] = nv;  // lowest-index tie preserved
                    else {
                        rlist[cb][atomicAdd(&nrec[cb], 1)] = t;
                        values_l[t] = MAXD;
                        marked_l[t] = 1;
                    }
                } else if (t < m1) {  // col m1 got nv in row t
                    if (nv < v) { values_l[t] = nv; indices_l[t] = m1; }
                    else if (nv == v && m1 < idx) indices_l[t] = m1;  // jnp.argmin tie-break
                }
            }
        }
        barrier_lds_only();  // B2: LDS-only; row-m1 store drains under P3

        // ================= P3 =================
        if (t == m1) cs_l[m1] = ncs;  // nobody reads cs_l[m1] in P3
        const int n = nrec[cb];
        if (t == 0) nrec[pb] = 0;

        if (wid == 0) {
            // col store early: wave0's scan is LDS-only, store drains under it
            if (do_st) dc[(size_t)t * D + m1] = make_float2(nv, ncx);
            if (lane == 0) {
                // cut decision (f64 accumulators)
                double merge_e = within_l[m1] + within_l[m2] + (double)s_cross12;
                double e_sum = energy_l[m1] + energy_l[m2];
                int take = (merge_e >= e_sum) ? 1 : 0;
                within_l[m1] = merge_e;
                energy_l[m1] = take ? merge_e : e_sum;
                s_takeP = take;
                s_m1P = m1;
                s_labP = D + it;
            }
            // full argmin scan of values_l (marked rows are MAXD and stable;
            // their true keys come from wave1/rescan publishers)
            const float4* v4 = (const float4*)values_l;
            u64 bb = ~0ull;  // (val<<32)|row during reduce
#pragma unroll
            for (int c = 0; c < 4; ++c) {
                int fi = lane + 64 * c;
                float4 q = v4[fi];
                int b = fi << 2;
                u64 k;
                k = ((u64)__float_as_uint(q.x) << 32) | (u32)(b + 0); if (k < bb) bb = k;
                k = ((u64)__float_as_uint(q.y) << 32) | (u32)(b + 1); if (k < bb) bb = k;
                k = ((u64)__float_as_uint(q.z) << 32) | (u32)(b + 2); if (k < bb) bb = k;
                k = ((u64)__float_as_uint(q.w) << 32) | (u32)(b + 3); if (k < bb) bb = k;
            }
            for (int o = 32; o; o >>= 1) {
                u64 k2 = __shfl_xor(bb, o);
                if (k2 < bb) bb = k2;
            }
            if (lane == 0) {
                int r = (int)(bb & 1023);
                int idx = indices_l[r];  // r is unmarked -> stable during P3
                atomicMin(&s_best[pb],
                          (bb & 0xffffffff00000000ull) | ((u32)r << 10) | (u32)idx);
            }
            // speculative prefetch of the candidate pair's rows (likely next
            // m1/m2). One dword per 64B segment covers every cache line of
            // both 8KB rows. Values consumed by the asm sink after B3, where
            // vmcnt is already 0 -> zero added wait.
            {
                int r_pf = (int)(bb & 1023);
                int i_pf = indices_l[r_pf];
                const float* br = (const float*)(dc + (size_t)r_pf * D);
                const float* bi = (const float*)(dc + (size_t)i_pf * D);
                pf0 = br[lane * 16];
                pf1 = br[1024 + lane * 16];
                pf2 = bi[lane * 16];
                pf3 = bi[1024 + lane * 16];
            }
        } else if (wid == 1) {
            // col store early: wave1's scan is LDS-only, store drains under it
            if (do_st) dc[(size_t)t * D + m1] = make_float2(nv, ncx);
            // row m1's new min from LDS newv_l (dead cols are MAXD by construction)
            u64 bb = ((u64)MAXDb << 32);  // (val<<32)|col
            const float4* nv4 = (const float4*)newv_l;
            for (int c = lane; c < D / 4; c += 64) {
                float4 q = nv4[c];
                int j0 = c << 2;
#pragma unroll
                for (int e = 0; e < 4; ++e) {
                    int j = j0 + e;
                    float dv = (e == 0) ? q.x : (e == 1) ? q.y : (e == 2) ? q.z : q.w;
                    if (j > m1) {
                        u64 k = ((u64)__float_as_uint(dv) << 32) | (u32)j;
                        if (k < bb) bb = k;
                    }
                }
            }
            for (int o = 32; o; o >>= 1) {
                u64 k2 = __shfl_xor(bb, o);
                if (k2 < bb) bb = k2;
            }
            if (lane == 0) {
                values_stage[m1] = __uint_as_float((u32)(bb >> 32));
                indices_l[m1] = (int)(bb & 0xffffffffu);
                atomicMin(&s_best[pb],
                          (bb & 0xffffffff00000000ull) | ((u32)m1 << 10) | (bb & 1023));
            }
            // NEW: prefetch the fresh-merge candidate pair (m1, j*). All lanes
            // hold bb after the butterfly -> no broadcast needed. Covers the
            // common mispredict where the just-merged cluster wins the argmin.
            // Row m1 is L2-dirty (just stored); warming both costs 4 loads.
            {
                int j_pf = (int)(bb & 1023);
                const float* bm = (const float*)(dc + (size_t)m1 * D);
                const float* bj = (const float*)(dc + (size_t)j_pf * D);
                pf0 = bm[lane * 16];
                pf1 = bm[1024 + lane * 16];
                pf2 = bj[lane * 16];
                pf3 = bj[1024 + lane * 16];
            }
        } else {
            // residual rescans (argmin retired/rose), one wave per row.
            // Row loads issue BEFORE the col store: in-order vmcnt means a
            // store-first ordering would stall load consumption on the
            // scattered store's RFO latency.
            bool pend_st = do_st;
            for (int q = wid - 2; q < n; q += 14) {
                const int r = rlist[cb][q];
                const float subst = newv_l[r];  // col-m1 value (store in flight)
                const float4* row4 = (const float4*)(dc + (size_t)r * D);
                float4 a0 = row4[lane];
                float4 a1 = row4[lane + 64];
                float4 a2 = row4[lane + 128];
                float4 a3 = row4[lane + 192];
                float4 a4 = row4[lane + 256];
                float4 a5 = row4[lane + 320];
                float4 a6 = row4[lane + 384];
                float4 a7 = row4[lane + 448];
                if (pend_st) {  // issue after loads; drains under the reduce
                    dc[(size_t)t * D + m1] = make_float2(nv, ncx);
                    pend_st = false;
                }
                u64 bb = ((u64)MAXDb << 32);  // (val<<32)|col
#define ACC2(af, koff)                                                          \
                {                                                               \
                    int j0 = (lane + (koff)) << 1;                              \
                    float dv0 = (j0 == m1) ? subst : (af).x;                    \
                    if (j0 > r && !dead_l[j0]) {                                \
                        u64 k = ((u64)__float_as_uint(dv0) << 32) | (u32)j0;    \
                        if (k < bb) bb = k;                                     \
                    }                                                           \
                    int j1 = j0 + 1;                                            \
                    float dv1 = (j1 == m1) ? subst : (af).z;                    \
                    if (j1 > r && !dead_l[j1]) {                                \
                        u64 k = ((u64)__float_as_uint(dv1) << 32) | (u32)j1;    \
                        if (k < bb) bb = k;                                     \
                    }                                                           \
                }
                ACC2(a0, 0)
                ACC2(a1, 64)
                ACC2(a2, 128)
                ACC2(a3, 192)
                ACC2(a4, 256)
                ACC2(a5, 320)
                ACC2(a6, 384)
                ACC2(a7, 448)
#undef ACC2
                for (int o = 32; o; o >>= 1) {
                    u64 k2 = __shfl_xor(bb, o);
                    if (k2 < bb) bb = k2;
                }
                if (lane == 0) {
                    values_stage[r] = __uint_as_float((u32)(bb >> 32));
                    indices_l[r] = (int)(bb & 0xffffffffu);
                    atomicMin(&s_best[pb],
                              (bb & 0xffffffff00000000ull) | ((u32)r << 10) | (bb & 1023));
                }
            }
            if (pend_st) dc[(size_t)t * D + m1] = make_float2(nv, ncx);
        }
        __syncthreads();  // B3: full drain; all waves' stores retire in parallel
        // keep the prefetch loads alive; vmcnt already 0 here -> free
        if (wid <= 1) asm volatile("" :: "v"(pf0), "v"(pf1), "v"(pf2), "v"(pf3));
    }

    // apply the final iteration's deferred cut, then emit labels
    {
        int lab = label_l[t];
        if (s_takeP && slot_l[t] == s_m1P) lab = s_labP;
        labels_g[t] = lab;
    }
}

// ---------- kernel D: R[a][b] = (a==b) || (label[a]==label[b]) ----------
__global__ void k_out(const int* __restrict__ labels, float* __restrict__ out) {
    int idx = blockIdx.x * blockDim.x + threadIdx.x;
    if (idx >= D * D) return;
    int i = idx >> 10, j = idx & (D - 1);
    out[idx] = (i == j || labels[i] == labels[j]) ? 1.0f : 0.0f;
}

extern "C" void kernel_launch(void* const* d_in, const int* in_sizes, int n_in,
                              void* d_out, int out_size, void* d_ws, size_t ws_size,
                              hipStream_t stream) {
    const float* X = (const float*)d_in[0];
    const float* W = (const float*)d_in[1];

    char* ws = (char*)d_ws;
    const size_t MAT_BYTES = (size_t)D * D * sizeof(float);  // 4 MiB
    float2* dc = (float2*)ws;                                // 8 MiB interleaved
    float* values_g = (float*)(ws + 2 * MAT_BYTES);
    int* indices_g = (int*)(ws + 2 * MAT_BYTES + 4096);
    int* labels_g = (int*)(ws + 2 * MAT_BYTES + 8192);
    u32* scal = (u32*)(ws + 2 * MAT_BYTES + 12288);

    hipMemsetAsync(scal, 0, 2 * sizeof(u32), stream);
    k_maxred<<<256, 256, 0, stream>>>(X, scal);
    k_init<<<(D * D) / 256, 256, 0, stream>>>(X, W, dc, scal);
    k_rowmin<<<D, 64, 0, stream>>>(dc, values_g, indices_g, scal);
    k_hac<<<1, 1024, 0, stream>>>(dc, values_g, indices_g, labels_g, scal);
    k_out<<<(D * D) / 256, 256, 0, stream>>>(labels_g, (float*)d_out);
}